// Round 1
// baseline (1842.446 us; speedup 1.0000x reference)
//
#include <hip/hip_runtime.h>
#include <hip/hip_bf16.h>

#define HIDDEN 256
#define H2 128
#define NCOLS 384          // 128 gate-hidden cols + 256 value cols
#define NUM_GRAPHS 8192
#define GPB 2              // graphs per block (sorted batch => contiguous rows)

typedef short bf16x8 __attribute__((ext_vector_type(8)));
typedef float f32x4 __attribute__((ext_vector_type(4)));

__device__ __forceinline__ unsigned short f32_bf16_rne(float f) {
  union { float f; unsigned int u; } v; v.f = f;
  unsigned int u = v.u;
  unsigned int lsb = (u >> 16) & 1u;
  u += 0x7fffu + lsb;
  return (unsigned short)(u >> 16);
}

__device__ __forceinline__ float silu_f(float h) {
  return h / (1.0f + __expf(-h));
}

// seg[g] = first node index whose batch >= g ; seg[NUM_GRAPHS] = N
__global__ void seg_starts_kernel(const int* __restrict__ batch,
                                  int* __restrict__ seg, int N) {
  int i = blockIdx.x * blockDim.x + threadIdx.x;
  if (i >= N) return;
  int cur = batch[i];
  int prev = (i == 0) ? -1 : batch[i - 1];
  for (int g = prev + 1; g <= cur; ++g) seg[g] = i;
  if (i == N - 1)
    for (int g = cur + 1; g <= NUM_GRAPHS; ++g) seg[g] = N;
}

// Wt2[(k>>3)*NCOLS*8 + n*8 + (k&7)] = bf16(W[k][n]); W = [w_g1 | w_v]
// This layout makes a wave's MFMA B-fragment load fully coalesced from global.
__global__ void convert_w_kernel(const float* __restrict__ w_g1,
                                 const float* __restrict__ w_v,
                                 unsigned short* __restrict__ Wt2) {
  int idx = blockIdx.x * blockDim.x + threadIdx.x;   // 0 .. 98303
  int j  = idx & 7;
  int n  = (idx >> 3) % NCOLS;
  int kc = idx / (NCOLS * 8);
  int k  = kc * 8 + j;
  float v = (n < H2) ? w_g1[k * H2 + n] : w_v[k * HIDDEN + (n - H2)];
  Wt2[idx] = f32_bf16_rne(v);
}

__launch_bounds__(256, 2)
__global__ void attn_readout_kernel(
    const float* __restrict__ x,
    const int* __restrict__ batch,
    const float* __restrict__ b_g1,
    const float* __restrict__ w_g2,
    const float* __restrict__ b_g2,
    const float* __restrict__ b_v,
    const unsigned short* __restrict__ Wt2,
    const int* __restrict__ seg,
    float* __restrict__ out)
{
  // row stride 264 (+8 bf16 pad): frag-read lanes land 2-way on banks (free)
  __shared__ unsigned short As[64 * 264];
  __shared__ float out_acc[GPB * 256];
  __shared__ float denom_s[GPB];
  __shared__ float gate_part[4][64];
  __shared__ float es[64];
  __shared__ int   gis[64];

  const int tid  = threadIdx.x;
  const int w    = tid >> 6;        // wave 0..3
  const int lane = tid & 63;
  const int l15  = lane & 15;
  const int quad = lane >> 4;

  const int g0      = blockIdx.x * GPB;
  const int node_lo = seg[g0];
  const int node_hi = seg[g0 + GPB];

  for (int i = tid; i < GPB * 256; i += 256) out_acc[i] = 0.0f;
  if (tid < GPB) denom_s[tid] = 0.0f;

  // per-lane constants: wave w owns n-tiles {w, w+4, ..., w+20}
  float bg1r[2], wg2r[2], bvr[4];
#pragma unroll
  for (int i = 0; i < 2; ++i) {
    int col = (w + 4 * i) * 16 + l15;          // gate cols [0,128)
    bg1r[i] = b_g1[col];
    wg2r[i] = w_g2[col];
  }
#pragma unroll
  for (int i = 0; i < 4; ++i) {
    int colv = (w + 4 * (i + 2)) * 16 + l15 - 128;  // value cols [0,256)
    bvr[i] = b_v[colv];
  }
  const float bg2 = b_g2[0];

  for (int node0 = node_lo; node0 < node_hi; node0 += 64) {
    // ---- stage A: 64 rows x 256 f32 -> bf16 LDS (zero-pad past node_hi) ----
#pragma unroll
    for (int rep = 0; rep < 16; ++rep) {
      int v   = rep * 256 + tid;       // float4 index: wave reads 1 KB rows
      int row = v >> 6;
      int c4  = v & 63;
      int node = node0 + row;
      float4 val = make_float4(0.f, 0.f, 0.f, 0.f);
      if (node < node_hi)
        val = *(const float4*)(x + ((size_t)node << 8) + (c4 << 2));
      ushort4 u;
      u.x = f32_bf16_rne(val.x); u.y = f32_bf16_rne(val.y);
      u.z = f32_bf16_rne(val.z); u.w = f32_bf16_rne(val.w);
      *(ushort4*)&As[row * 264 + (c4 << 2)] = u;
    }
    __syncthreads();   // S0

    // ---- GEMM: [64x256] @ [256x384], B frags straight from L2-hot global ----
    f32x4 acc[4][6];
#pragma unroll
    for (int mt = 0; mt < 4; ++mt)
#pragma unroll
      for (int tn = 0; tn < 6; ++tn)
        acc[mt][tn] = (f32x4){0.f, 0.f, 0.f, 0.f};

#pragma unroll
    for (int c = 0; c < 8; ++c) {
      bf16x8 a[4];
#pragma unroll
      for (int mt = 0; mt < 4; ++mt)
        a[mt] = *(const bf16x8*)&As[(mt * 16 + l15) * 264 + c * 32 + quad * 8];
      int kc = c * 4 + quad;
#pragma unroll
      for (int tn = 0; tn < 6; ++tn) {
        int n = (w + 4 * tn) * 16 + l15;
        bf16x8 b = *(const bf16x8*)(Wt2 + (((kc * NCOLS) + n) << 3));
#pragma unroll
        for (int mt = 0; mt < 4; ++mt)
          acc[mt][tn] = __builtin_amdgcn_mfma_f32_16x16x32_bf16(
              a[mt], b, acc[mt][tn], 0, 0, 0);
      }
    }

    // ---- gate: silu(h)@w_g2, reduce 16 lanes (cols) per quad ----
    float p[4][4];
#pragma unroll
    for (int mt = 0; mt < 4; ++mt)
#pragma unroll
      for (int r = 0; r < 4; ++r) p[mt][r] = 0.f;
#pragma unroll
    for (int tn = 0; tn < 2; ++tn)
#pragma unroll
      for (int mt = 0; mt < 4; ++mt)
#pragma unroll
        for (int r = 0; r < 4; ++r) {
          float h = acc[mt][tn][r] + bg1r[tn];
          p[mt][r] += silu_f(h) * wg2r[tn];
        }
#pragma unroll
    for (int off = 1; off < 16; off <<= 1)
#pragma unroll
      for (int mt = 0; mt < 4; ++mt)
#pragma unroll
        for (int r = 0; r < 4; ++r)
          p[mt][r] += __shfl_xor(p[mt][r], off, 64);
    if (l15 == 0)
#pragma unroll
      for (int mt = 0; mt < 4; ++mt)
#pragma unroll
        for (int r = 0; r < 4; ++r)
          gate_part[w][mt * 16 + quad * 4 + r] = p[mt][r];
    __syncthreads();   // S1

    // ---- e = exp(gate) (no max-shift: gates are O(1)); per-row graph id ----
    if (tid < 64) {
      int row = tid;
      float g = gate_part[0][row] + gate_part[1][row] +
                gate_part[2][row] + gate_part[3][row] + bg2;
      int node = node0 + row;
      float e = 0.f; int gi = 0;
      if (node < node_hi) {
        e  = __expf(g);
        gi = batch[node] - g0;
        atomicAdd(&denom_s[gi], e);
      }
      es[row] = e; gis[row] = gi;
    }
    __syncthreads();   // S2

    // ---- weighted value accumulate: out_acc[gi][col] += e * silu(v) ----
    float e_r[4][4]; int gi_r[4][4];
#pragma unroll
    for (int mt = 0; mt < 4; ++mt)
#pragma unroll
      for (int r = 0; r < 4; ++r) {
        int row = mt * 16 + quad * 4 + r;
        e_r[mt][r]  = es[row];
        gi_r[mt][r] = gis[row];
      }
#pragma unroll
    for (int tn = 2; tn < 6; ++tn) {
      int colv = (w + 4 * tn) * 16 + l15 - 128;
      float bias = bvr[tn - 2];
#pragma unroll
      for (int mt = 0; mt < 4; ++mt)
#pragma unroll
        for (int r = 0; r < 4; ++r) {
          float e = e_r[mt][r];
          if (e != 0.f) {
            float h = acc[mt][tn][r] + bias;
            atomicAdd(&out_acc[gi_r[mt][r] * 256 + colv], e * silu_f(h));
          }
        }
    }
  }

  __syncthreads();
  for (int i = tid; i < GPB * 256; i += 256) {
    int gi = i >> 8;
    out[(size_t)(g0 + gi) * 256 + (i & 255)] =
        out_acc[i] / (denom_s[gi] + 1e-16f);
  }
}

extern "C" void kernel_launch(void* const* d_in, const int* in_sizes, int n_in,
                              void* d_out, int out_size, void* d_ws, size_t ws_size,
                              hipStream_t stream) {
  const float* x    = (const float*)d_in[0];
  const int*   batch= (const int*)d_in[1];
  const float* w_g1 = (const float*)d_in[2];
  const float* b_g1 = (const float*)d_in[3];
  const float* w_g2 = (const float*)d_in[4];
  const float* b_g2 = (const float*)d_in[5];
  const float* w_v  = (const float*)d_in[6];
  const float* b_v  = (const float*)d_in[7];
  float* out = (float*)d_out;
  const int N = in_sizes[0] / HIDDEN;

  unsigned short* Wt2 = (unsigned short*)d_ws;                       // 192 KB
  int* seg = (int*)((char*)d_ws + (size_t)NCOLS * HIDDEN * sizeof(unsigned short));

  seg_starts_kernel<<<(N + 255) / 256, 256, 0, stream>>>(batch, seg, N);
  convert_w_kernel<<<(NCOLS * HIDDEN) / 256, 256, 0, stream>>>(w_g1, w_v, Wt2);
  attn_readout_kernel<<<NUM_GRAPHS / GPB, 256, 0, stream>>>(
      x, batch, b_g1, w_g2, b_g2, b_v, Wt2, seg, out);
}

// Round 2
// 1300.377 us; speedup vs baseline: 1.4169x; 1.4169x over previous
//
#include <hip/hip_runtime.h>
#include <hip/hip_bf16.h>

#define HIDDEN 256
#define H2 128
#define NCOLS 384          // 128 gate-hidden cols + 256 value cols
#define NUM_GRAPHS 8192
#define GPB 2              // graphs per block (sorted batch => contiguous rows)

typedef short bf16x8 __attribute__((ext_vector_type(8)));
typedef float f32x4 __attribute__((ext_vector_type(4)));

__device__ __forceinline__ unsigned short f32_bf16_rne(float f) {
  union { float f; unsigned int u; } v; v.f = f;
  unsigned int u = v.u;
  unsigned int lsb = (u >> 16) & 1u;
  u += 0x7fffu + lsb;
  return (unsigned short)(u >> 16);
}

__device__ __forceinline__ float silu_f(float h) {
  return h / (1.0f + __expf(-h));
}

// seg[g] = first node index whose batch >= g ; seg[NUM_GRAPHS] = N
__global__ void seg_starts_kernel(const int* __restrict__ batch,
                                  int* __restrict__ seg, int N) {
  int i = blockIdx.x * blockDim.x + threadIdx.x;
  if (i >= N) return;
  int cur = batch[i];
  int prev = (i == 0) ? -1 : batch[i - 1];
  for (int g = prev + 1; g <= cur; ++g) seg[g] = i;
  if (i == N - 1)
    for (int g = cur + 1; g <= NUM_GRAPHS; ++g) seg[g] = N;
}

// Wt2[(k>>3)*NCOLS*8 + n*8 + (k&7)] = bf16(W[k][n]); W = [w_g1 | w_v]
// Layout makes a wave's MFMA B-fragment load fully coalesced from global/L2.
__global__ void convert_w_kernel(const float* __restrict__ w_g1,
                                 const float* __restrict__ w_v,
                                 unsigned short* __restrict__ Wt2) {
  int idx = blockIdx.x * blockDim.x + threadIdx.x;   // 0 .. 98303
  int j  = idx & 7;
  int n  = (idx >> 3) % NCOLS;
  int kc = idx / (NCOLS * 8);
  int k  = kc * 8 + j;
  float v = (n < H2) ? w_g1[k * H2 + n] : w_v[k * HIDDEN + (n - H2)];
  Wt2[idx] = f32_bf16_rne(v);
}

// 4 blocks/CU: LDS 35 KB * 4 = 140 <= 160 KB; VGPR cap 128 (peak live ~105:
// value acc 64 + a-frags 16 + vacc 8 + consts). Phase-split GEMM keeps us
// under the cap -- R1's fused epilogue needed 144+ and spilled 680 MB.
__launch_bounds__(256, 4)
__global__ void attn_readout_kernel(
    const float* __restrict__ x,
    const float* __restrict__ b_g1,
    const float* __restrict__ w_g2,
    const float* __restrict__ b_g2,
    const float* __restrict__ b_v,
    const unsigned short* __restrict__ Wt2,
    const int* __restrict__ seg,
    float* __restrict__ out)
{
  // row stride 264 shorts (+8 pad)
  __shared__ unsigned short As[64 * 264];
  __shared__ float gate_part[4][64];
  __shared__ float es[64];
  __shared__ float denom_s[2];

  const int tid  = threadIdx.x;
  const int w    = tid >> 6;        // wave 0..3
  const int lane = tid & 63;
  const int l15  = lane & 15;
  const int quad = lane >> 4;

  const int g0      = blockIdx.x * GPB;
  const int node_lo = seg[g0];
  const int split   = seg[g0 + 1];   // first node of graph g0+1
  const int node_hi = seg[g0 + 2];

  // per-lane constants: wave w owns n-tiles {w, w+4, ..., w+20}
  float bg1r[2], wg2r[2], bvr[4];
#pragma unroll
  for (int i = 0; i < 2; ++i) {
    int col = (w + 4 * i) * 16 + l15;               // gate cols [0,128)
    bg1r[i] = b_g1[col];
    wg2r[i] = w_g2[col];
  }
#pragma unroll
  for (int i = 0; i < 4; ++i) {
    int colv = (w + 4 * (i + 2)) * 16 + l15 - 128;  // value cols [0,256)
    bvr[i] = b_v[colv];
  }
  const float bg2 = b_g2[0];

  // persistent accumulators (registers, no LDS atomics)
  float vacc0[4] = {0.f, 0.f, 0.f, 0.f};
  float vacc1[4] = {0.f, 0.f, 0.f, 0.f};
  float d0 = 0.f, d1 = 0.f;          // denominators (wave 0, lane==row)

  for (int node0 = node_lo; node0 < node_hi; node0 += 64) {
    // ---- stage A: 64 rows x 256 f32 -> bf16 LDS (zero-pad past node_hi) ---
#pragma unroll 4
    for (int rep = 0; rep < 16; ++rep) {
      int v   = rep * 256 + tid;     // float4 index; wave covers 1 KB rows
      int row = v >> 6;
      int c4  = v & 63;
      int node = node0 + row;
      float4 val = make_float4(0.f, 0.f, 0.f, 0.f);
      if (node < node_hi)
        val = *(const float4*)(x + ((size_t)node << 8) + (c4 << 2));
      ushort4 u;
      u.x = f32_bf16_rne(val.x); u.y = f32_bf16_rne(val.y);
      u.z = f32_bf16_rne(val.z); u.w = f32_bf16_rne(val.w);
      *(ushort4*)&As[row * 264 + (c4 << 2)] = u;
    }
    __syncthreads();   // S0: As ready

    // ---- phase 1: gate GEMM [64x256]@[256x128] (acc 32 regs) ----
    {
      f32x4 accg[4][2];
#pragma unroll
      for (int mt = 0; mt < 4; ++mt)
#pragma unroll
        for (int tn = 0; tn < 2; ++tn)
          accg[mt][tn] = (f32x4){0.f, 0.f, 0.f, 0.f};

#pragma unroll
      for (int c = 0; c < 8; ++c) {
        bf16x8 a[4];
#pragma unroll
        for (int mt = 0; mt < 4; ++mt)
          a[mt] = *(const bf16x8*)&As[(mt * 16 + l15) * 264 + c * 32 + quad * 8];
        int kc = c * 4 + quad;
#pragma unroll
        for (int tn = 0; tn < 2; ++tn) {
          int n = (w + 4 * tn) * 16 + l15;
          bf16x8 b = *(const bf16x8*)(Wt2 + (((kc * NCOLS) + n) << 3));
#pragma unroll
          for (int mt = 0; mt < 4; ++mt)
            accg[mt][tn] = __builtin_amdgcn_mfma_f32_16x16x32_bf16(
                a[mt], b, accg[mt][tn], 0, 0, 0);
        }
      }

      // silu(h) @ w_g2, butterfly over the 16 col-lanes of each quad
      float p[4][4];
#pragma unroll
      for (int mt = 0; mt < 4; ++mt)
#pragma unroll
        for (int r = 0; r < 4; ++r) {
          float s = 0.f;
#pragma unroll
          for (int tn = 0; tn < 2; ++tn) {
            float h = accg[mt][tn][r] + bg1r[tn];
            s += silu_f(h) * wg2r[tn];
          }
          p[mt][r] = s;
        }
#pragma unroll
      for (int off = 1; off < 16; off <<= 1)
#pragma unroll
        for (int mt = 0; mt < 4; ++mt)
#pragma unroll
          for (int r = 0; r < 4; ++r)
            p[mt][r] += __shfl_xor(p[mt][r], off, 64);
      if (l15 == 0)
#pragma unroll
        for (int mt = 0; mt < 4; ++mt)
#pragma unroll
          for (int r = 0; r < 4; ++r)
            gate_part[w][mt * 16 + quad * 4 + r] = p[mt][r];
    }
    __syncthreads();   // S1: gate partials ready

    // ---- e = exp(gate); no max-shift (gates are O(1)); denom in regs ----
    if (tid < 64) {
      int row = tid;
      int node = node0 + row;
      float e = 0.f;
      if (node < node_hi) {
        float g = gate_part[0][row] + gate_part[1][row] +
                  gate_part[2][row] + gate_part[3][row] + bg2;
        e = __expf(g);
        if (node < split) d0 += e; else d1 += e;
      }
      es[row] = e;
    }
    __syncthreads();   // S2: es ready

    // ---- phase 2: value GEMM [64x256]@[256x256] (acc 64 regs) + fold ----
    {
      f32x4 accv[4][4];
#pragma unroll
      for (int mt = 0; mt < 4; ++mt)
#pragma unroll
        for (int tn = 0; tn < 4; ++tn)
          accv[mt][tn] = (f32x4){0.f, 0.f, 0.f, 0.f};

#pragma unroll
      for (int c = 0; c < 8; ++c) {
        bf16x8 a[4];
#pragma unroll
        for (int mt = 0; mt < 4; ++mt)
          a[mt] = *(const bf16x8*)&As[(mt * 16 + l15) * 264 + c * 32 + quad * 8];
        int kc = c * 4 + quad;
#pragma unroll
        for (int tn = 0; tn < 4; ++tn) {
          int n = (w + 4 * (tn + 2)) * 16 + l15;
          bf16x8 b = *(const bf16x8*)(Wt2 + (((kc * NCOLS) + n) << 3));
#pragma unroll
          for (int mt = 0; mt < 4; ++mt)
            accv[mt][tn] = __builtin_amdgcn_mfma_f32_16x16x32_bf16(
                a[mt], b, accv[mt][tn], 0, 0, 0);
        }
      }

      // fold: vacc[gi][tn] += e * silu(v); gi from sorted-row split, branchless
#pragma unroll
      for (int mt = 0; mt < 4; ++mt)
#pragma unroll
        for (int r = 0; r < 4; ++r) {
          int row  = mt * 16 + quad * 4 + r;
          int node = node0 + row;
          float e  = es[row];                  // 0 for padded rows
          float se0 = (node < split) ? e : 0.f;
          float se1 = e - se0;
#pragma unroll
          for (int tn = 0; tn < 4; ++tn) {
            float s = silu_f(accv[mt][tn][r] + bvr[tn]);
            vacc0[tn] += se0 * s;
            vacc1[tn] += se1 * s;
          }
        }
    }
    __syncthreads();   // S3: done reading As/es before next staging
  }

  // ---- final reductions & store ----
#pragma unroll
  for (int tn = 0; tn < 4; ++tn) {
    vacc0[tn] += __shfl_xor(vacc0[tn], 16, 64);
    vacc0[tn] += __shfl_xor(vacc0[tn], 32, 64);
    vacc1[tn] += __shfl_xor(vacc1[tn], 16, 64);
    vacc1[tn] += __shfl_xor(vacc1[tn], 32, 64);
  }
  if (w == 0) {
#pragma unroll
    for (int off = 1; off < 64; off <<= 1) {
      d0 += __shfl_xor(d0, off, 64);
      d1 += __shfl_xor(d1, off, 64);
    }
    if (lane == 0) { denom_s[0] = d0; denom_s[1] = d1; }
  }
  __syncthreads();

  if (quad == 0) {
    float inv0 = 1.0f / (denom_s[0] + 1e-16f);
    float inv1 = 1.0f / (denom_s[1] + 1e-16f);
#pragma unroll
    for (int tn = 0; tn < 4; ++tn) {
      int colv = (w + 4 * (tn + 2)) * 16 + l15 - 128;
      out[(size_t)g0 * 256 + colv]       = vacc0[tn] * inv0;
      out[(size_t)(g0 + 1) * 256 + colv] = vacc1[tn] * inv1;
    }
  }
}

extern "C" void kernel_launch(void* const* d_in, const int* in_sizes, int n_in,
                              void* d_out, int out_size, void* d_ws, size_t ws_size,
                              hipStream_t stream) {
  const float* x    = (const float*)d_in[0];
  const int*   batch= (const int*)d_in[1];
  const float* w_g1 = (const float*)d_in[2];
  const float* b_g1 = (const float*)d_in[3];
  const float* w_g2 = (const float*)d_in[4];
  const float* b_g2 = (const float*)d_in[5];
  const float* w_v  = (const float*)d_in[6];
  const float* b_v  = (const float*)d_in[7];
  float* out = (float*)d_out;
  const int N = in_sizes[0] / HIDDEN;

  unsigned short* Wt2 = (unsigned short*)d_ws;                       // 192 KB
  int* seg = (int*)((char*)d_ws + (size_t)NCOLS * HIDDEN * sizeof(unsigned short));

  seg_starts_kernel<<<(N + 255) / 256, 256, 0, stream>>>(batch, seg, N);
  convert_w_kernel<<<(NCOLS * HIDDEN) / 256, 256, 0, stream>>>(w_g1, w_v, Wt2);
  attn_readout_kernel<<<NUM_GRAPHS / GPB, 256, 0, stream>>>(
      x, b_g1, w_g2, b_g2, b_v, Wt2, seg, out);
}